// Round 2
// baseline (180.226 us; speedup 1.0000x reference)
//
#include <hip/hip_runtime.h>

#define RES 128
#define NSTEPS 320
#define STEP 0.01f
// alpha > 0.01  <=>  1 - exp(-occ*STEP) > 0.01  <=>  occ > -ln(0.99)/STEP
// exact monotone transform; occ in [0,1) so boundary (1.00503) is unreachable
#define OCC_THRE 1.0050336f

#define SPT 4                 // samples per thread
#define TPR (NSTEPS / SPT)    // 80 threads per ray
#define BLOCK 256

__global__ __launch_bounds__(BLOCK) void nerfacc_sampler_kernel(
    const float* __restrict__ origins,     // [N,3]
    const float* __restrict__ dirs,        // [N,3]
    const float* __restrict__ occs,        // [RES,RES,RES]
    const float* __restrict__ aabb,        // [2,3]
    float* __restrict__ out,               // 7*N*S floats
    int N)
{
    const int T = blockIdx.x * BLOCK + threadIdx.x;
    const int r = T / TPR;
    if (r >= N) return;
    const int j0 = (T - r * TPR) * SPT;

    const float ox = origins[r * 3 + 0];
    const float oy = origins[r * 3 + 1];
    const float oz = origins[r * 3 + 2];
    const float dx = dirs[r * 3 + 0];
    const float dy = dirs[r * 3 + 1];
    const float dz = dirs[r * 3 + 2];
    const float lx = aabb[0], ly = aabb[1], lz = aabb[2];
    const float hx = aabb[3], hy = aabb[4], hz = aabb[5];

    // robust slab intersection (same arithmetic as R1, which matched exactly)
    const float sdx = (fabsf(dx) < 1e-10f) ? 1e-10f : dx;
    const float sdy = (fabsf(dy) < 1e-10f) ? 1e-10f : dy;
    const float sdz = (fabsf(dz) < 1e-10f) ? 1e-10f : dz;
    const float ivx = 1.0f / sdx, ivy = 1.0f / sdy, ivz = 1.0f / sdz;
    const float t0x = (lx - ox) * ivx, t1x = (hx - ox) * ivx;
    const float t0y = (ly - oy) * ivy, t1y = (hy - oy) * ivy;
    const float t0z = (lz - oz) * ivz, t1z = (hz - oz) * ivz;
    float tmin = fmaxf(fmaxf(fminf(t0x, t1x), fminf(t0y, t1y)), fminf(t0z, t1z));
    float tmax = fminf(fminf(fmaxf(t0x, t1x), fmaxf(t0y, t1y)), fmaxf(t0z, t1z));
    tmin = fmaxf(tmin, 0.0f);   // NEAR = 0

    float px[SPT], py[SPT], pz[SPT], ts[SPT], te[SPT], ri[SPT], mm[SPT];
    float occv[SPT];

    // phase 1: addresses + gathers (independent -> ILP hides latency)
    int gidx[SPT];
    float uxv[SPT], uyv[SPT], uzv[SPT];
    #pragma unroll
    for (int i = 0; i < SPT; ++i) {
        const float t_start = tmin + (float)(j0 + i) * STEP;
        const float t_end   = t_start + STEP;
        const float t_mid   = 0.5f * (t_start + t_end);
        const float x = ox + dx * t_mid;
        const float y = oy + dy * t_mid;
        const float z = oz + dz * t_mid;
        const float ux = (x - lx) / (hx - lx);
        const float uy = (y - ly) / (hy - ly);
        const float uz = (z - lz) / (hz - lz);
        int ix = min(max((int)floorf(ux * (float)RES), 0), RES - 1);
        int iy = min(max((int)floorf(uy * (float)RES), 0), RES - 1);
        int iz = min(max((int)floorf(uz * (float)RES), 0), RES - 1);
        gidx[i] = (ix * RES + iy) * RES + iz;
        uxv[i] = ux; uyv[i] = uy; uzv[i] = uz;
        px[i] = x; py[i] = y; pz[i] = z;
        ts[i] = t_start; te[i] = t_end;
    }
    #pragma unroll
    for (int i = 0; i < SPT; ++i) occv[i] = occs[gidx[i]];

    // phase 2: mask + compaction
    #pragma unroll
    for (int i = 0; i < SPT; ++i) {
        const bool inside = (uxv[i] >= 0.0f) & (uxv[i] < 1.0f) &
                            (uyv[i] >= 0.0f) & (uyv[i] < 1.0f) &
                            (uzv[i] >= 0.0f) & (uzv[i] < 1.0f);
        const bool mask = inside & (te[i] <= tmax) & (occv[i] > OCC_THRE) & (tmax > tmin);
        const float m = mask ? 1.0f : 0.0f;
        px[i] *= m; py[i] *= m; pz[i] *= m;
        ts[i] *= m; te[i] *= m;
        ri[i] = mask ? (float)r : -1.0f;
        mm[i] = m;
    }

    // phase 3: vectorized stores — all float4, 16 B/lane, coalesced
    const size_t NS   = (size_t)N * NSTEPS;
    const size_t base = (size_t)r * NSTEPS + (size_t)j0;

    float4* pp = (float4*)(out + base * 3);          // 48 B contiguous, 16B-aligned
    pp[0] = make_float4(px[0], py[0], pz[0], px[1]);
    pp[1] = make_float4(py[1], pz[1], px[2], py[2]);
    pp[2] = make_float4(pz[2], px[3], py[3], pz[3]);

    *(float4*)(out + NS * 3 + base) = make_float4(ts[0], ts[1], ts[2], ts[3]);
    *(float4*)(out + NS * 4 + base) = make_float4(te[0], te[1], te[2], te[3]);
    *(float4*)(out + NS * 5 + base) = make_float4(ri[0], ri[1], ri[2], ri[3]);
    *(float4*)(out + NS * 6 + base) = make_float4(mm[0], mm[1], mm[2], mm[3]);
}

extern "C" void kernel_launch(void* const* d_in, const int* in_sizes, int n_in,
                              void* d_out, int out_size, void* d_ws, size_t ws_size,
                              hipStream_t stream) {
    const float* origins = (const float*)d_in[0];
    const float* dirs    = (const float*)d_in[1];
    const float* occs    = (const float*)d_in[2];
    const float* aabb    = (const float*)d_in[3];
    float* out = (float*)d_out;

    const int N = in_sizes[0] / 3;              // 16384
    const int total = N * TPR;                  // 1,310,720 threads
    const int grid = (total + BLOCK - 1) / BLOCK;

    nerfacc_sampler_kernel<<<dim3(grid), dim3(BLOCK), 0, stream>>>(
        origins, dirs, occs, aabb, out, N);
}